// Round 1
// baseline (1438.841 us; speedup 1.0000x reference)
//
#include <hip/hip_runtime.h>
#include <cstdint>

// ---------------- problem dims (fixed by the reference) ----------------
static constexpr int Mdim = 8192;     // B*S = 4*2048
static constexpr int Ndim = 11008;    // O
static constexpr int Kdim = 4096;     // I
static constexpr int NGRP = 32;       // I / 128

#define BM 128
#define BN 128
#define BK 64

typedef __bf16 bf16x8 __attribute__((ext_vector_type(8)));
typedef float floatx4 __attribute__((ext_vector_type(4)));
typedef unsigned short ushort8_t __attribute__((ext_vector_type(8)));

// RTNE fp32 -> bf16 (inputs are finite; no NaN path needed)
__device__ __forceinline__ unsigned short f2bf(float f) {
  union { float f; uint32_t u; } v; v.f = f;
  uint32_t u = v.u;
  return (unsigned short)((u + 0x7fffu + ((u >> 16) & 1u)) >> 16);
}

// async global->LDS, 16B per lane; LDS dest = wave-uniform base + lane*16
__device__ __forceinline__ void gload16(const void* g, void* l) {
  __builtin_amdgcn_global_load_lds(
      (const __attribute__((address_space(1))) void*)g,
      (__attribute__((address_space(3))) void*)l, 16, 0, 0);
}

// ---------------- prepass 1: x fp32 -> bf16 ----------------
__global__ __launch_bounds__(256) void cast_x_kernel(const float* __restrict__ x,
                                                     unsigned short* __restrict__ xb) {
  int i = blockIdx.x * 256 + threadIdx.x;   // 4 floats / thread
  float4 f = ((const float4*)x)[i];
  ushort4 o;
  o.x = f2bf(f.x); o.y = f2bf(f.y); o.z = f2bf(f.z); o.w = f2bf(f.w);
  ((ushort4*)xb)[i] = o;
}

// ---------------- prepass 2: dequant int4 -> bf16, W[N][K] ----------------
// qweight int32 [O][K/2]; col j holds nibbles for cols (2j, 2j+1); group = (2j)/128
__global__ __launch_bounds__(256) void dequant_w_kernel(const int* __restrict__ qw,
                                                        const float* __restrict__ scale,
                                                        const float* __restrict__ zp,
                                                        unsigned short* __restrict__ wb) {
  int idx = blockIdx.x * 256 + threadIdx.x;   // [0, O*512): 4 int32 / thread
  int o  = idx >> 9;
  int j4 = idx & 511;          // chunk of 4 int32 => 8 weights
  int g  = j4 >> 4;            // (j4*4)/64 : 4-int chunks never straddle a group
  float s = scale[o * NGRP + g];
  float z = zp[o * NGRP + g];
  int4 q = ((const int4*)qw)[idx];
  int qs[4] = {q.x, q.y, q.z, q.w};
  ushort8_t r;
#pragma unroll
  for (int t = 0; t < 4; ++t) {
    float lo = (float)(qs[t] & 15);
    float hi = (float)((qs[t] >> 4) & 15);
    r[2 * t]     = f2bf((lo - z) * s);
    r[2 * t + 1] = f2bf((hi - z) * s);
  }
  *(ushort8_t*)(wb + (size_t)o * Kdim + (size_t)j4 * 8) = r;
}

// ---------------- GEMM: C[M][N] = Xb[M][K] * Wb[N][K]^T + bias ----------------
__global__ __launch_bounds__(256, 2) void gemm_kernel(const unsigned short* __restrict__ Xb,
                                                      const unsigned short* __restrict__ Wb,
                                                      const float* __restrict__ bias,
                                                      float* __restrict__ out) {
  __shared__ unsigned short As[BM * BK];
  __shared__ unsigned short Bs[BN * BK];

  const int tid  = threadIdx.x;
  const int wave = tid >> 6;
  const int lane = tid & 63;
  const int wm   = wave & 1;    // 2x2 wave grid, each wave 64x64
  const int wn   = wave >> 1;

  const int row0 = blockIdx.y * BM;
  const int col0 = blockIdx.x * BN;

  // staging: each wave stages 32 rows (4 calls x 8 rows); lane -> row +lane/8, col (lane%8)*8
  const int srow = wave * 32 + (lane >> 3);
  const int scol = (lane & 7) * 8;

  const unsigned short* ag = Xb + (size_t)(row0 + srow) * Kdim + scol;
  const unsigned short* bg = Wb + (size_t)(col0 + srow) * Kdim + scol;
  unsigned short* al = &As[(wave * 32) * BK];
  unsigned short* bl = &Bs[(wave * 32) * BK];

  floatx4 acc[4][4];
#pragma unroll
  for (int i = 0; i < 4; ++i)
#pragma unroll
    for (int j = 0; j < 4; ++j) acc[i][j] = (floatx4){0.f, 0.f, 0.f, 0.f};

  for (int k0 = 0; k0 < Kdim; k0 += BK) {
#pragma unroll
    for (int i = 0; i < 4; ++i) {
      gload16(ag + (size_t)(i * 8) * Kdim, al + i * 8 * BK);
      gload16(bg + (size_t)(i * 8) * Kdim, bl + i * 8 * BK);
    }
    ag += BK; bg += BK;
    __syncthreads();   // compiler drains vmcnt(0) before s_barrier

#pragma unroll
    for (int kk = 0; kk < BK; kk += 32) {
      bf16x8 af[4], bfr[4];
#pragma unroll
      for (int t = 0; t < 4; ++t) {
        af[t]  = *(const bf16x8*)&As[(wm * 64 + t * 16 + (lane & 15)) * BK + kk + (lane >> 4) * 8];
        bfr[t] = *(const bf16x8*)&Bs[(wn * 64 + t * 16 + (lane & 15)) * BK + kk + (lane >> 4) * 8];
      }
#pragma unroll
      for (int tm = 0; tm < 4; ++tm)
#pragma unroll
        for (int tn = 0; tn < 4; ++tn)
          acc[tm][tn] = __builtin_amdgcn_mfma_f32_16x16x32_bf16(af[tm], bfr[tn], acc[tm][tn], 0, 0, 0);
    }
    __syncthreads();
  }

  // epilogue: C/D layout col=lane&15, row=(lane>>4)*4+reg
  const int m_base = row0 + wm * 64;
  const int n_base = col0 + wn * 64;
#pragma unroll
  for (int tn = 0; tn < 4; ++tn) {
    const int n = n_base + tn * 16 + (lane & 15);
    const float bv = bias[n];
#pragma unroll
    for (int tm = 0; tm < 4; ++tm) {
      const int m0 = m_base + tm * 16 + (lane >> 4) * 4;
#pragma unroll
      for (int r = 0; r < 4; ++r)
        out[(size_t)(m0 + r) * Ndim + n] = acc[tm][tn][r] + bv;
    }
  }
}

extern "C" void kernel_launch(void* const* d_in, const int* in_sizes, int n_in,
                              void* d_out, int out_size, void* d_ws, size_t ws_size,
                              hipStream_t stream) {
  const float* x     = (const float*)d_in[0];
  const int*   qw    = (const int*)d_in[1];
  const float* scale = (const float*)d_in[2];
  const float* zp    = (const float*)d_in[3];
  const float* bias  = (const float*)d_in[4];
  float* out = (float*)d_out;

  // workspace layout: Xb[M*K] bf16 (64 MiB), then Wb[N*K] bf16 (86 MiB) => 150 MiB total
  unsigned short* xb = (unsigned short*)d_ws;
  unsigned short* wb = xb + (size_t)Mdim * Kdim;

  cast_x_kernel<<<(Mdim * Kdim / 4) / 256, 256, 0, stream>>>(x, xb);
  dequant_w_kernel<<<(Ndim * 512) / 256, 256, 0, stream>>>(qw, scale, zp, wb);
  gemm_kernel<<<dim3(Ndim / BN, Mdim / BM), 256, 0, stream>>>(xb, wb, bias, out);
}

// Round 2
// 1203.513 us; speedup vs baseline: 1.1955x; 1.1955x over previous
//
#include <hip/hip_runtime.h>
#include <cstdint>

// ---------------- problem dims (fixed by the reference) ----------------
static constexpr int Mdim = 8192;     // B*S = 4*2048
static constexpr int Ndim = 11008;    // O
static constexpr int Kdim = 4096;     // I
static constexpr int NGRP = 32;       // I / 128

#define BM 128
#define BN 128
#define BK 64

typedef __bf16 bf16x8 __attribute__((ext_vector_type(8)));
typedef float floatx4 __attribute__((ext_vector_type(4)));
typedef unsigned short ushort8_t __attribute__((ext_vector_type(8)));

// RTNE fp32 -> bf16 (inputs are finite; no NaN path needed)
__device__ __forceinline__ unsigned short f2bf(float f) {
  union { float f; uint32_t u; } v; v.f = f;
  uint32_t u = v.u;
  return (unsigned short)((u + 0x7fffu + ((u >> 16) & 1u)) >> 16);
}

// async global->LDS, 16B per lane; LDS dest = wave-uniform base + lane*16
__device__ __forceinline__ void gload16(const void* g, void* l) {
  __builtin_amdgcn_global_load_lds(
      (const __attribute__((address_space(1))) void*)g,
      (__attribute__((address_space(3))) void*)l, 16, 0, 0);
}

// ---------------- prepass 1: x fp32 -> bf16 ----------------
__global__ __launch_bounds__(256) void cast_x_kernel(const float* __restrict__ x,
                                                     unsigned short* __restrict__ xb) {
  int i = blockIdx.x * 256 + threadIdx.x;   // 4 floats / thread
  float4 f = ((const float4*)x)[i];
  ushort4 o;
  o.x = f2bf(f.x); o.y = f2bf(f.y); o.z = f2bf(f.z); o.w = f2bf(f.w);
  ((ushort4*)xb)[i] = o;
}

// ---------------- prepass 2: dequant int4 -> bf16, W[N][K] ----------------
__global__ __launch_bounds__(256) void dequant_w_kernel(const int* __restrict__ qw,
                                                        const float* __restrict__ scale,
                                                        const float* __restrict__ zp,
                                                        unsigned short* __restrict__ wb) {
  int idx = blockIdx.x * 256 + threadIdx.x;   // [0, O*512): 4 int32 / thread
  int o  = idx >> 9;
  int j4 = idx & 511;          // chunk of 4 int32 => 8 weights
  int g  = j4 >> 4;            // 4-int chunks never straddle a group
  float s = scale[o * NGRP + g];
  float z = zp[o * NGRP + g];
  int4 q = ((const int4*)qw)[idx];
  int qs[4] = {q.x, q.y, q.z, q.w};
  ushort8_t r;
#pragma unroll
  for (int t = 0; t < 4; ++t) {
    float lo = (float)(qs[t] & 15);
    float hi = (float)((qs[t] >> 4) & 15);
    r[2 * t]     = f2bf((lo - z) * s);
    r[2 * t + 1] = f2bf((hi - z) * s);
  }
  *(ushort8_t*)(wb + (size_t)o * Kdim + (size_t)j4 * 8) = r;
}

// ---------------- GEMM: C[M][N] = Xb[M][K] * Wb[N][K]^T + bias ----------------
// LDS layout is XOR-swizzled: element (row, chunk c) of the tile lives at LDS
// chunk c ^ (row & 7)  (chunk = 16 B = 8 bf16). Staging picks the global
// source chunk per lane so global_load_lds's fixed base+lane*16 dest realizes
// this layout; fragment reads apply the same XOR. Kills the 16-way bank
// conflict of the unswizzled 128 B-row-stride layout.
__global__ __launch_bounds__(256, 2) void gemm_kernel(const unsigned short* __restrict__ Xb,
                                                      const unsigned short* __restrict__ Wb,
                                                      const float* __restrict__ bias,
                                                      float* __restrict__ out) {
  __shared__ unsigned short As[BM * BK];
  __shared__ unsigned short Bs[BN * BK];

  const int tid  = threadIdx.x;
  const int wave = tid >> 6;
  const int lane = tid & 63;
  const int wm   = wave & 1;    // 2x2 wave grid, each wave 64x64
  const int wn   = wave >> 1;

  // grid: x = M-blocks (fast), y = N-blocks -> consecutive blocks share one
  // W col-block and sweep X; X (64 MB) stays LLC-resident, W fetched ~once.
  const int row0 = blockIdx.x * BM;
  const int col0 = blockIdx.y * BN;

  // staging: each wave stages 32 rows (4 calls x 8 rows)
  const int srow = wave * 32 + (lane >> 3);
  const int sw   = (lane >> 3) & 7;                  // row & 7
  const int scol = (((lane & 7) ^ sw) << 3);         // swizzled source chunk

  const unsigned short* ag = Xb + (size_t)(row0 + srow) * Kdim + scol;
  const unsigned short* bg = Wb + (size_t)(col0 + srow) * Kdim + scol;
  unsigned short* al = &As[(wave * 32) * BK];
  unsigned short* bl = &Bs[(wave * 32) * BK];

  floatx4 acc[4][4];
#pragma unroll
  for (int i = 0; i < 4; ++i)
#pragma unroll
    for (int j = 0; j < 4; ++j) acc[i][j] = (floatx4){0.f, 0.f, 0.f, 0.f};

  for (int k0 = 0; k0 < Kdim; k0 += BK) {
#pragma unroll
    for (int i = 0; i < 4; ++i) {
      gload16(ag + (size_t)(i * 8) * Kdim, al + i * 8 * BK);
      gload16(bg + (size_t)(i * 8) * Kdim, bl + i * 8 * BK);
    }
    ag += BK; bg += BK;
    __syncthreads();

#pragma unroll
    for (int kk = 0; kk < BK; kk += 32) {
      bf16x8 af[4], bfr[4];
#pragma unroll
      for (int t = 0; t < 4; ++t) {
        // fragment row r = ...+ (lane&15): r&7 == lane&7; chunk = kk/8 + quad
        const int co = ((((kk >> 3) + (lane >> 4)) ^ (lane & 7)) << 3);
        af[t]  = *(const bf16x8*)&As[(wm * 64 + t * 16 + (lane & 15)) * BK + co];
        bfr[t] = *(const bf16x8*)&Bs[(wn * 64 + t * 16 + (lane & 15)) * BK + co];
      }
#pragma unroll
      for (int tm = 0; tm < 4; ++tm)
#pragma unroll
        for (int tn = 0; tn < 4; ++tn)
          acc[tm][tn] = __builtin_amdgcn_mfma_f32_16x16x32_bf16(af[tm], bfr[tn], acc[tm][tn], 0, 0, 0);
    }
    __syncthreads();
  }

  // epilogue: C/D layout col=lane&15, row=(lane>>4)*4+reg
  const int m_base = row0 + wm * 64;
  const int n_base = col0 + wn * 64;
#pragma unroll
  for (int tn = 0; tn < 4; ++tn) {
    const int n = n_base + tn * 16 + (lane & 15);
    const float bv = bias[n];
#pragma unroll
    for (int tm = 0; tm < 4; ++tm) {
      const int m0 = m_base + tm * 16 + (lane >> 4) * 4;
#pragma unroll
      for (int r = 0; r < 4; ++r)
        out[(size_t)(m0 + r) * Ndim + n] = acc[tm][tn][r] + bv;
    }
  }
}

extern "C" void kernel_launch(void* const* d_in, const int* in_sizes, int n_in,
                              void* d_out, int out_size, void* d_ws, size_t ws_size,
                              hipStream_t stream) {
  const float* x     = (const float*)d_in[0];
  const int*   qw    = (const int*)d_in[1];
  const float* scale = (const float*)d_in[2];
  const float* zp    = (const float*)d_in[3];
  const float* bias  = (const float*)d_in[4];
  float* out = (float*)d_out;

  // workspace: Xb[M*K] bf16 (64 MiB), then Wb[N*K] bf16 (86 MiB)
  unsigned short* xb = (unsigned short*)d_ws;
  unsigned short* wb = xb + (size_t)Mdim * Kdim;

  cast_x_kernel<<<(Mdim * Kdim / 4) / 256, 256, 0, stream>>>(x, xb);
  dequant_w_kernel<<<(Ndim * 512) / 256, 256, 0, stream>>>(qw, scale, zp, wb);
  gemm_kernel<<<dim3(Mdim / BM, Ndim / BN), 256, 0, stream>>>(xb, wb, bias, out);
}